// Round 3
// baseline (339.258 us; speedup 1.0000x reference)
//
#include <hip/hip_runtime.h>
#include <hip/hip_bf16.h>
#include <stdint.h>

// Problem constants
#define M_B   1536      // 64*24 batch rows
#define N_L   500       // links
#define N_LP  512       // padded links (K of GEMM1, N of GEMM2)
#define N_P   20000     // paths
#define N_PP  20096     // padded paths (N of GEMM1 = 157*128, K of GEMM2)
#define N_G   4000      // OD groups
#define SPLITK 16
#define KCHUNK2 1280    // split-K chunk for GEMM2 (last chunk = 896, both %32==0)
#define NQ    4         // row split for softmax (quarters)
#define GQ    (N_G / NQ)   // 1000 groups per block
#define SM_CAP 7168     // LDS floats per softmax block (quarter ~5000, sigma~61 -> huge margin)

// Workspace layout (bytes). Total ~228 MB. partial aliases vp (vp dead after softmax).
#define OFF_A1   ((size_t)0)                    // bf16 [1536][512]      1,572,864
#define OFF_D1   ((size_t)1572864)              // bf16 [512][20096]    20,578,304
#define OFF_DT   ((size_t)22151168)             // bf16 [20096][512]    20,578,304
#define OFF_VP   ((size_t)42729472)             // f32  [1536][20096]  123,469,824
#define OFF_PART OFF_VP                         // f32  [16][1536][512] 50,331,648 (aliases vp)
#define OFF_F    ((size_t)166199296)            // bf16 [1536][20096]   61,734,912
#define OFF_BND  ((size_t)227934208)            // int  [4001]

typedef __bf16 bf16x8 __attribute__((ext_vector_type(8)));
typedef __bf16 bf16x4 __attribute__((ext_vector_type(4)));
typedef float  f32x4  __attribute__((ext_vector_type(4)));

__device__ __forceinline__ void gload16(const void* g, void* l) {
  __builtin_amdgcn_global_load_lds(
      (const __attribute__((address_space(1))) void*)g,
      (__attribute__((address_space(3))) void*)l, 16, 0, 0);
}

// ---- prep: v_links -> bf16 A1 [1536][512], zero-padded ----
__global__ __launch_bounds__(256) void prep_a1(const float* __restrict__ X,
                                               const float* __restrict__ theta,
                                               const float* __restrict__ theta_links,
                                               __bf16* __restrict__ A1) {
  int idx = blockIdx.x * 256 + threadIdx.x;           // over 1536*512
  if (idx >= M_B * N_LP) return;
  int b = idx >> 9, l = idx & (N_LP - 1);
  float v = 0.f;
  if (l < N_L) {
    const float* x = X + ((size_t)b * N_L + l) * 5;
#pragma unroll
    for (int f = 0; f < 5; ++f) v += x[f] * fminf(theta[f], 0.f);
    v += theta_links[l];
  }
  A1[idx] = (__bf16)v;
}

// ---- prep: D -> bf16 D1 [512][20096] (row copy) AND Dt [20096][512] (transpose),
//      both zero-padded; D read once. 32x32 tiles. ----
__global__ __launch_bounds__(256) void prep_d(const float* __restrict__ D,
                                              __bf16* __restrict__ D1,
                                              __bf16* __restrict__ Dt) {
  __shared__ float t[32][33];
  int pb = blockIdx.x * 32;   // path block
  int lb = blockIdx.y * 32;   // link block
  for (int i = threadIdx.y; i < 32; i += 8) {
    int l = lb + i, p = pb + threadIdx.x;
    float v = (l < N_L && p < N_P) ? D[(size_t)l * N_P + p] : 0.f;
    t[i][threadIdx.x] = v;
    D1[(size_t)l * N_PP + p] = (__bf16)v;
  }
  __syncthreads();
  for (int i = threadIdx.y; i < 32; i += 8) {
    int p = pb + i, l = lb + threadIdx.x;
    Dt[(size_t)p * N_LP + l] = (__bf16)t[threadIdx.x][i];
  }
}

// ---- segment bounds: bounds[g] = first path index with seg >= g, g in [0,4000] ----
__global__ __launch_bounds__(256) void seg_bounds(const int* __restrict__ seg,
                                                  int* __restrict__ bounds) {
  int g = blockIdx.x * 256 + threadIdx.x;
  if (g > N_G) return;
  int lo = 0, hi = N_P;
  while (lo < hi) { int mid = (lo + hi) >> 1; if (seg[mid] < g) lo = mid + 1; else hi = mid; }
  bounds[g] = lo;
}

// ---- GEMM (both A and Bt row-major over K): C[m][n] = sum_k A[m][k]*Bt[n][k] ----
__global__ __launch_bounds__(256) void gemm_bt(const __bf16* __restrict__ A,
                                               const __bf16* __restrict__ Bt,
                                               float* __restrict__ C,
                                               int lda, int ldb, int ldc,
                                               int K, int kchunk, size_t zstride) {
  __shared__ __bf16 lsA[128 * 32];
  __shared__ __bf16 lsB[128 * 32];
  const int tid = threadIdx.x;
  const int lane = tid & 63;
  const int wv = tid >> 6;
  const int wr = wv >> 1, wc = wv & 1;
  const int m0 = blockIdx.y * 128;
  const int n0 = blockIdx.x * 128;
  const int kb = blockIdx.z * kchunk;
  const int klen = min(kchunk, K - kb);

  const int srow = wv * 16 + (lane >> 2);
  const int scol = (lane & 3) * 8;
  const __bf16* gA = A + (size_t)(m0 + srow) * lda + kb + scol;
  const __bf16* gB = Bt + (size_t)(n0 + srow) * ldb + kb + scol;
  __bf16* lA0 = &lsA[(wv * 16) * 32];
  __bf16* lA1 = &lsA[(64 + wv * 16) * 32];
  __bf16* lB0 = &lsB[(wv * 16) * 32];
  __bf16* lB1 = &lsB[(64 + wv * 16) * 32];

  f32x4 acc[4][4] = {};
  const int fra = (wr * 64 + (lane & 15)) * 32 + 8 * (lane >> 4);
  const int frb = (wc * 64 + (lane & 15)) * 32 + 8 * (lane >> 4);

  for (int kk = 0; kk < klen; kk += 32) {
    gload16(gA + kk, lA0);
    gload16(gA + (size_t)64 * lda + kk, lA1);
    gload16(gB + kk, lB0);
    gload16(gB + (size_t)64 * ldb + kk, lB1);
    __syncthreads();
    bf16x8 av[4], bv[4];
#pragma unroll
    for (int r = 0; r < 4; ++r) av[r] = *(const bf16x8*)&lsA[fra + r * 16 * 32];
#pragma unroll
    for (int c = 0; c < 4; ++c) bv[c] = *(const bf16x8*)&lsB[frb + c * 16 * 32];
#pragma unroll
    for (int r = 0; r < 4; ++r)
#pragma unroll
      for (int c = 0; c < 4; ++c)
        acc[r][c] = __builtin_amdgcn_mfma_f32_16x16x32_bf16(av[r], bv[c], acc[r][c], 0, 0, 0);
    __syncthreads();
  }

  float* Cz = C + (size_t)blockIdx.z * zstride;
  const int erow = m0 + wr * 64 + (lane >> 4) * 4;
  const int ecol = n0 + wc * 64 + (lane & 15);
#pragma unroll
  for (int r = 0; r < 4; ++r)
#pragma unroll
    for (int c = 0; c < 4; ++c) {
      float* p = Cz + (size_t)(erow + r * 16) * ldc + (ecol + c * 16);
#pragma unroll
      for (int j = 0; j < 4; ++j) p[(size_t)j * ldc] = acc[r][c][j];
    }
}

// ---- grouped softmax, lane-parallel. blockIdx.x = row b, blockIdx.y = quarter ----
// Quarter covers groups [q*GQ, (q+1)*GQ) and paths [bounds[g0], bounds[g1)).
// 8-lane clusters reduce one group each (shfl_xor butterflies); final pass is
// vectorized: f32x4 LDS read, int4 seg read, per-group scale lookup, bf16x4 store.
__global__ __launch_bounds__(256) void seg_softmax(const float* __restrict__ vp,
                                                   const int* __restrict__ bounds,
                                                   const int* __restrict__ seg,
                                                   const float* __restrict__ q_sqrt,
                                                   __bf16* __restrict__ f) {
  __shared__ float sr[SM_CAP];
  __shared__ int   sbnd[GQ + 4];
  __shared__ float ssc[GQ];
  const int tid = threadIdx.x;
  const int b = blockIdx.x;
  const int g0 = blockIdx.y * GQ, g1 = g0 + GQ;

  // stage bounds[g0..g1] into LDS
  for (int i = tid; i <= GQ; i += 256) sbnd[i] = bounds[g0 + i];
  __syncthreads();

  const int s0 = sbnd[0];
  const int e0 = sbnd[GQ];
  const int s0a = s0 & ~3;
  const int e0a = (e0 + 3) & ~3;
  const float* row = vp + (size_t)b * N_PP;

  // coalesced float4 load of [s0a, e0a)
  for (int i = s0a / 4 + tid; i * 4 < e0a; i += 256)
    *(f32x4*)&sr[i * 4 - s0a] = *(const f32x4*)&row[i * 4];
  __syncthreads();

#define LR(p) sr[(p) - s0a]
  // 8-lane clusters: cluster cl handles groups g0+cl, g0+cl+32, ...
  const int cl = tid >> 3;
  const int li = tid & 7;
  for (int gg = cl; gg < GQ; gg += 32) {
    int s = sbnd[gg], e = sbnd[gg + 1];
    float m = -3.4e38f;
    for (int p = s + li; p < e; p += 8) m = fmaxf(m, LR(p));
    m = fmaxf(m, __shfl_xor(m, 1));
    m = fmaxf(m, __shfl_xor(m, 2));
    m = fmaxf(m, __shfl_xor(m, 4));
    float den = 0.f;
    for (int p = s + li; p < e; p += 8) {
      float t = __expf(LR(p) - m);
      LR(p) = t;
      den += t;
    }
    den += __shfl_xor(den, 1);
    den += __shfl_xor(den, 2);
    den += __shfl_xor(den, 4);
    if (li == 0 && s < e) {
      float qs = q_sqrt[g0 + gg];
      ssc[gg] = qs * qs / den;
    }
  }
  __syncthreads();

  __bf16* frow = f + (size_t)b * N_PP;
  // scalar head to 4-alignment
  const int s0w = (s0 + 3) & ~3;
  for (int p = s0 + tid; p < min(s0w, e0); p += 256)
    frow[p] = (__bf16)(LR(p) * ssc[seg[p] - g0]);
  // vectorized middle
  const int e0w = e0 & ~3;
  for (int i = s0w / 4 + tid; i * 4 < e0w; i += 256) {
    int p = i * 4;
    f32x4 v = *(const f32x4*)&LR(p);
    int4 sg = *(const int4*)&seg[p];
    bf16x4 o;
    o[0] = (__bf16)(v[0] * ssc[sg.x - g0]);
    o[1] = (__bf16)(v[1] * ssc[sg.y - g0]);
    o[2] = (__bf16)(v[2] * ssc[sg.z - g0]);
    o[3] = (__bf16)(v[3] * ssc[sg.w - g0]);
    *(bf16x4*)&frow[p] = o;
  }
  // scalar tail
  for (int p = max(e0w, s0w) + tid; p < e0; p += 256)
    frow[p] = (__bf16)(LR(p) * ssc[seg[p] - g0]);
  // zero padded tail so GEMM2's K-padding contributes nothing
  if (blockIdx.y == NQ - 1)
    for (int p = N_P + tid; p < N_PP; p += 256) frow[p] = (__bf16)0.f;
#undef LR
}

// ---- reduce split-K partials -> out (only l < 500) ----
__global__ __launch_bounds__(256) void reduce_out(const float* __restrict__ part,
                                                  float* __restrict__ out) {
  int idx = blockIdx.x * 256 + threadIdx.x;   // over 1536*500
  if (idx >= M_B * N_L) return;
  int b = idx / N_L, l = idx - b * N_L;
  float s = 0.f;
#pragma unroll
  for (int z = 0; z < SPLITK; ++z)
    s += part[(size_t)z * M_B * N_LP + (size_t)b * N_LP + l];
  out[idx] = s;
}

extern "C" void kernel_launch(void* const* d_in, const int* in_sizes, int n_in,
                              void* d_out, int out_size, void* d_ws, size_t ws_size,
                              hipStream_t stream) {
  const float* X           = (const float*)d_in[0];
  const float* theta       = (const float*)d_in[1];
  const float* theta_links = (const float*)d_in[2];
  const float* q_sqrt      = (const float*)d_in[3];
  const float* D           = (const float*)d_in[4];
  const int*   seg         = (const int*)d_in[5];
  float* out = (float*)d_out;

  char* ws = (char*)d_ws;
  __bf16* A1   = (__bf16*)(ws + OFF_A1);
  __bf16* D1   = (__bf16*)(ws + OFF_D1);
  __bf16* Dt   = (__bf16*)(ws + OFF_DT);
  float*  vp   = (float*)(ws + OFF_VP);
  float*  part = (float*)(ws + OFF_PART);
  __bf16* fbuf = (__bf16*)(ws + OFF_F);
  int*    bnd  = (int*)(ws + OFF_BND);

  prep_a1<<<(M_B * N_LP) / 256, 256, 0, stream>>>(X, theta, theta_links, A1);
  prep_d<<<dim3(N_PP / 32, N_LP / 32), dim3(32, 8), 0, stream>>>(D, D1, Dt);
  seg_bounds<<<16, 256, 0, stream>>>(seg, bnd);

  // GEMM1: vp[b][p] = sum_l A1[b][l] * Dt[p][l]
  gemm_bt<<<dim3(N_PP / 128, M_B / 128, 1), 256, 0, stream>>>(
      A1, Dt, vp, N_LP, N_LP, N_PP, N_LP, N_LP, (size_t)0);

  seg_softmax<<<dim3(M_B, NQ), 256, 0, stream>>>(vp, bnd, seg, q_sqrt, fbuf);

  // GEMM2 (split-K): part[z][b][l] = sum_{k in chunk z} f[b][k] * D1[l][k]
  gemm_bt<<<dim3(N_LP / 128, M_B / 128, SPLITK), 256, 0, stream>>>(
      fbuf, D1, part, N_PP, N_PP, N_LP, N_PP, KCHUNK2, (size_t)(M_B * N_LP));

  reduce_out<<<(M_B * N_L + 255) / 256, 256, 0, stream>>>(part, out);
}

// Round 4
// 269.481 us; speedup vs baseline: 1.2589x; 1.2589x over previous
//
#include <hip/hip_runtime.h>
#include <hip/hip_bf16.h>
#include <stdint.h>

// Problem constants
#define M_B   1536      // 64*24 batch rows
#define N_L   500       // links
#define N_LP  512       // padded links (K of GEMM1, N of GEMM2)
#define N_P   20000     // paths
#define N_PP  20096     // padded paths (N of GEMM1 = 157*128, K of GEMM2)
#define N_G   4000      // OD groups
#define SPLITK 16
#define KCHUNK2 1280    // split-K chunk for GEMM2 (last chunk = 896, both %32==0)
#define NQ    4         // row split for softmax (quarters)
#define GQ    (N_G / NQ)   // 1000 groups per block
#define MAXC  7         // max f32x4 chunks per thread (7*1024=7168 paths >= 5000+35sigma)

// Workspace layout (bytes). Total ~228 MB. partial aliases vp (vp dead after softmax).
#define OFF_A1   ((size_t)0)                    // bf16 [1536][512]      1,572,864
#define OFF_D1   ((size_t)1572864)              // bf16 [512][20096]    20,578,304
#define OFF_DT   ((size_t)22151168)             // bf16 [20096][512]    20,578,304
#define OFF_VP   ((size_t)42729472)             // f32  [1536][20096]  123,469,824
#define OFF_PART OFF_VP                         // f32  [16][1536][512] 50,331,648 (aliases vp)
#define OFF_F    ((size_t)166199296)            // bf16 [1536][20096]   61,734,912
#define OFF_BND  ((size_t)227934208)            // int  [4001]

typedef __bf16 bf16x8 __attribute__((ext_vector_type(8)));
typedef __bf16 bf16x4 __attribute__((ext_vector_type(4)));
typedef float  f32x4  __attribute__((ext_vector_type(4)));

__device__ __forceinline__ void gload16(const void* g, void* l) {
  __builtin_amdgcn_global_load_lds(
      (const __attribute__((address_space(1))) void*)g,
      (__attribute__((address_space(3))) void*)l, 16, 0, 0);
}

// monotonic float<->uint order-preserving mapping (for ds_max_u32-based float max)
__device__ __forceinline__ unsigned f2mono(float x) {
  unsigned u = __float_as_uint(x);
  return (u & 0x80000000u) ? ~u : (u | 0x80000000u);
}
__device__ __forceinline__ float mono2f(unsigned u) {
  u = (u & 0x80000000u) ? (u & 0x7fffffffu) : ~u;
  return __uint_as_float(u);
}

// ---- prep: v_links -> bf16 A1 [1536][512], zero-padded ----
__global__ __launch_bounds__(256) void prep_a1(const float* __restrict__ X,
                                               const float* __restrict__ theta,
                                               const float* __restrict__ theta_links,
                                               __bf16* __restrict__ A1) {
  int idx = blockIdx.x * 256 + threadIdx.x;           // over 1536*512
  if (idx >= M_B * N_LP) return;
  int b = idx >> 9, l = idx & (N_LP - 1);
  float v = 0.f;
  if (l < N_L) {
    const float* x = X + ((size_t)b * N_L + l) * 5;
#pragma unroll
    for (int f = 0; f < 5; ++f) v += x[f] * fminf(theta[f], 0.f);
    v += theta_links[l];
  }
  A1[idx] = (__bf16)v;
}

// ---- prep: D -> bf16 D1 [512][20096] (row copy) AND Dt [20096][512] (transpose),
//      both zero-padded; D read once. 32x32 tiles. ----
__global__ __launch_bounds__(256) void prep_d(const float* __restrict__ D,
                                              __bf16* __restrict__ D1,
                                              __bf16* __restrict__ Dt) {
  __shared__ float t[32][33];
  int pb = blockIdx.x * 32;   // path block
  int lb = blockIdx.y * 32;   // link block
  for (int i = threadIdx.y; i < 32; i += 8) {
    int l = lb + i, p = pb + threadIdx.x;
    float v = (l < N_L && p < N_P) ? D[(size_t)l * N_P + p] : 0.f;
    t[i][threadIdx.x] = v;
    D1[(size_t)l * N_PP + p] = (__bf16)v;
  }
  __syncthreads();
  for (int i = threadIdx.y; i < 32; i += 8) {
    int p = pb + i, l = lb + threadIdx.x;
    Dt[(size_t)p * N_LP + l] = (__bf16)t[threadIdx.x][i];
  }
}

// ---- segment bounds: bounds[g] = first path index with seg >= g, g in [0,4000] ----
__global__ __launch_bounds__(256) void seg_bounds(const int* __restrict__ seg,
                                                  int* __restrict__ bounds) {
  int g = blockIdx.x * 256 + threadIdx.x;
  if (g > N_G) return;
  int lo = 0, hi = N_P;
  while (lo < hi) { int mid = (lo + hi) >> 1; if (seg[mid] < g) lo = mid + 1; else hi = mid; }
  bounds[g] = lo;
}

// ---- GEMM (both A and Bt row-major over K): C[m][n] = sum_k A[m][k]*Bt[n][k] ----
__global__ __launch_bounds__(256) void gemm_bt(const __bf16* __restrict__ A,
                                               const __bf16* __restrict__ Bt,
                                               float* __restrict__ C,
                                               int lda, int ldb, int ldc,
                                               int K, int kchunk, size_t zstride) {
  __shared__ __bf16 lsA[128 * 32];
  __shared__ __bf16 lsB[128 * 32];
  const int tid = threadIdx.x;
  const int lane = tid & 63;
  const int wv = tid >> 6;
  const int wr = wv >> 1, wc = wv & 1;
  const int m0 = blockIdx.y * 128;
  const int n0 = blockIdx.x * 128;
  const int kb = blockIdx.z * kchunk;
  const int klen = min(kchunk, K - kb);

  const int srow = wv * 16 + (lane >> 2);
  const int scol = (lane & 3) * 8;
  const __bf16* gA = A + (size_t)(m0 + srow) * lda + kb + scol;
  const __bf16* gB = Bt + (size_t)(n0 + srow) * ldb + kb + scol;
  __bf16* lA0 = &lsA[(wv * 16) * 32];
  __bf16* lA1 = &lsA[(64 + wv * 16) * 32];
  __bf16* lB0 = &lsB[(wv * 16) * 32];
  __bf16* lB1 = &lsB[(64 + wv * 16) * 32];

  f32x4 acc[4][4] = {};
  const int fra = (wr * 64 + (lane & 15)) * 32 + 8 * (lane >> 4);
  const int frb = (wc * 64 + (lane & 15)) * 32 + 8 * (lane >> 4);

  for (int kk = 0; kk < klen; kk += 32) {
    gload16(gA + kk, lA0);
    gload16(gA + (size_t)64 * lda + kk, lA1);
    gload16(gB + kk, lB0);
    gload16(gB + (size_t)64 * ldb + kk, lB1);
    __syncthreads();
    bf16x8 av[4], bv[4];
#pragma unroll
    for (int r = 0; r < 4; ++r) av[r] = *(const bf16x8*)&lsA[fra + r * 16 * 32];
#pragma unroll
    for (int c = 0; c < 4; ++c) bv[c] = *(const bf16x8*)&lsB[frb + c * 16 * 32];
#pragma unroll
    for (int r = 0; r < 4; ++r)
#pragma unroll
      for (int c = 0; c < 4; ++c)
        acc[r][c] = __builtin_amdgcn_mfma_f32_16x16x32_bf16(av[r], bv[c], acc[r][c], 0, 0, 0);
    __syncthreads();
  }

  float* Cz = C + (size_t)blockIdx.z * zstride;
  const int erow = m0 + wr * 64 + (lane >> 4) * 4;
  const int ecol = n0 + wc * 64 + (lane & 15);
#pragma unroll
  for (int r = 0; r < 4; ++r)
#pragma unroll
    for (int c = 0; c < 4; ++c) {
      float* p = Cz + (size_t)(erow + r * 16) * ldc + (ecol + c * 16);
#pragma unroll
      for (int j = 0; j < 4; ++j) p[(size_t)j * ldc] = acc[r][c][j];
    }
}

// ---- grouped softmax, data-parallel over paths + LDS atomics for group reduce ----
// blockIdx.x = row b, blockIdx.y = quarter (groups [q*GQ,(q+1)*GQ), paths [bounds[g0], e0)).
// Values live in registers (MAXC statically-unrolled f32x4 chunks); group max via
// ds_max_u32 (monotonic uint map), denom via native ds_add_f32. No shuffles.
__global__ __launch_bounds__(256) void seg_softmax(const float* __restrict__ vp,
                                                   const int* __restrict__ bounds,
                                                   const int* __restrict__ seg,
                                                   const float* __restrict__ q_sqrt,
                                                   __bf16* __restrict__ f) {
  __shared__ unsigned gmaxu[GQ];
  __shared__ float    den[GQ];     // denom, then overwritten with scale q^2/denom
  const int tid = threadIdx.x;
  const int b = blockIdx.x;
  const int g0 = blockIdx.y * GQ;
  const int g1 = g0 + GQ;

  const unsigned NEGINF = f2mono(-3.4e38f);
  for (int i = tid; i < GQ; i += 256) { gmaxu[i] = NEGINF; den[i] = 0.f; }

  const int s0 = bounds[g0];
  const int e0 = (blockIdx.y == NQ - 1) ? N_P : bounds[g1];
  const int s0a = s0 & ~3;
  const int e0a = (e0 + 3) & ~3;
  const float* row = vp + (size_t)b * N_PP;

  f32x4 vv[MAXC];
  int4  sgv[MAXC];
  __syncthreads();   // init visible

  // load chunks (coalesced f32x4 + int4)
#pragma unroll
  for (int c = 0; c < MAXC; ++c) {
    int p = s0a + (c * 256 + tid) * 4;
    if (p < e0a) {
      vv[c] = *(const f32x4*)&row[p];
      sgv[c] = *(const int4*)&seg[p];
    }
  }

  // pass 1: per-chunk run-combine -> atomic max
#define AMAX(g, m) { if ((g) >= g0 && (g) < g1) atomicMax(&gmaxu[(g) - g0], f2mono(m)); }
#pragma unroll
  for (int c = 0; c < MAXC; ++c) {
    int p = s0a + (c * 256 + tid) * 4;
    if (p >= e0a) continue;
    int ga = sgv[c].x; float mv = vv[c][0];
    if (sgv[c].y == ga) mv = fmaxf(mv, vv[c][1]); else { AMAX(ga, mv); ga = sgv[c].y; mv = vv[c][1]; }
    if (sgv[c].z == ga) mv = fmaxf(mv, vv[c][2]); else { AMAX(ga, mv); ga = sgv[c].z; mv = vv[c][2]; }
    if (sgv[c].w == ga) mv = fmaxf(mv, vv[c][3]); else { AMAX(ga, mv); ga = sgv[c].w; mv = vv[c][3]; }
    AMAX(ga, mv);
  }
#undef AMAX
  __syncthreads();

  // pass 2: exp in registers + run-combine -> atomic add
#define AADD(g, s) { if ((g) >= g0 && (g) < g1) atomicAdd(&den[(g) - g0], s); }
#pragma unroll
  for (int c = 0; c < MAXC; ++c) {
    int p = s0a + (c * 256 + tid) * 4;
    if (p >= e0a) continue;
    float t[4];
#pragma unroll
    for (int j = 0; j < 4; ++j) {
      int g = (&sgv[c].x)[j];
      bool valid = (g >= g0 && g < g1);
      float gm = valid ? mono2f(gmaxu[g - g0]) : 0.f;
      float e = valid ? __expf(vv[c][j] - gm) : 0.f;
      t[j] = e;
      vv[c][j] = e;
    }
    int ga = sgv[c].x; float s = t[0];
    if (sgv[c].y == ga) s += t[1]; else { AADD(ga, s); ga = sgv[c].y; s = t[1]; }
    if (sgv[c].z == ga) s += t[2]; else { AADD(ga, s); ga = sgv[c].z; s = t[2]; }
    if (sgv[c].w == ga) s += t[3]; else { AADD(ga, s); ga = sgv[c].w; s = t[3]; }
    AADD(ga, s);
  }
#undef AADD
  __syncthreads();

  // den -> scale = q^2 / den
  for (int g = tid; g < GQ; g += 256) {
    float d = den[g];
    if (d > 0.f) {
      float qs = q_sqrt[g0 + g];
      den[g] = qs * qs / d;
    }
  }
  __syncthreads();

  // pass 3: scale + store (vector where the whole chunk is in-range)
  __bf16* frow = f + (size_t)b * N_PP;
#pragma unroll
  for (int c = 0; c < MAXC; ++c) {
    int p = s0a + (c * 256 + tid) * 4;
    if (p >= e0a) continue;
    bool allv = (sgv[c].x >= g0) && (sgv[c].w < g1);
    if (allv) {
      bf16x4 o;
      o[0] = (__bf16)(vv[c][0] * den[sgv[c].x - g0]);
      o[1] = (__bf16)(vv[c][1] * den[sgv[c].y - g0]);
      o[2] = (__bf16)(vv[c][2] * den[sgv[c].z - g0]);
      o[3] = (__bf16)(vv[c][3] * den[sgv[c].w - g0]);
      *(bf16x4*)&frow[p] = o;
    } else {
#pragma unroll
      for (int j = 0; j < 4; ++j) {
        int g = (&sgv[c].x)[j];
        if (g >= g0 && g < g1) frow[p + j] = (__bf16)(vv[c][j] * den[g - g0]);
      }
    }
  }
  // zero padded tail so GEMM2's K-padding contributes nothing
  if (blockIdx.y == NQ - 1)
    for (int p = N_P + tid; p < N_PP; p += 256) frow[p] = (__bf16)0.f;
}

// ---- reduce split-K partials -> out (only l < 500) ----
__global__ __launch_bounds__(256) void reduce_out(const float* __restrict__ part,
                                                  float* __restrict__ out) {
  int idx = blockIdx.x * 256 + threadIdx.x;   // over 1536*500
  if (idx >= M_B * N_L) return;
  int b = idx / N_L, l = idx - b * N_L;
  float s = 0.f;
#pragma unroll
  for (int z = 0; z < SPLITK; ++z)
    s += part[(size_t)z * M_B * N_LP + (size_t)b * N_LP + l];
  out[idx] = s;
}

extern "C" void kernel_launch(void* const* d_in, const int* in_sizes, int n_in,
                              void* d_out, int out_size, void* d_ws, size_t ws_size,
                              hipStream_t stream) {
  const float* X           = (const float*)d_in[0];
  const float* theta       = (const float*)d_in[1];
  const float* theta_links = (const float*)d_in[2];
  const float* q_sqrt      = (const float*)d_in[3];
  const float* D           = (const float*)d_in[4];
  const int*   seg         = (const int*)d_in[5];
  float* out = (float*)d_out;

  char* ws = (char*)d_ws;
  __bf16* A1   = (__bf16*)(ws + OFF_A1);
  __bf16* D1   = (__bf16*)(ws + OFF_D1);
  __bf16* Dt   = (__bf16*)(ws + OFF_DT);
  float*  vp   = (float*)(ws + OFF_VP);
  float*  part = (float*)(ws + OFF_PART);
  __bf16* fbuf = (__bf16*)(ws + OFF_F);
  int*    bnd  = (int*)(ws + OFF_BND);

  prep_a1<<<(M_B * N_LP) / 256, 256, 0, stream>>>(X, theta, theta_links, A1);
  prep_d<<<dim3(N_PP / 32, N_LP / 32), dim3(32, 8), 0, stream>>>(D, D1, Dt);
  seg_bounds<<<16, 256, 0, stream>>>(seg, bnd);

  // GEMM1: vp[b][p] = sum_l A1[b][l] * Dt[p][l]
  gemm_bt<<<dim3(N_PP / 128, M_B / 128, 1), 256, 0, stream>>>(
      A1, Dt, vp, N_LP, N_LP, N_PP, N_LP, N_LP, (size_t)0);

  seg_softmax<<<dim3(M_B, NQ), 256, 0, stream>>>(vp, bnd, seg, q_sqrt, fbuf);

  // GEMM2 (split-K): part[z][b][l] = sum_{k in chunk z} f[b][k] * D1[l][k]
  gemm_bt<<<dim3(N_LP / 128, M_B / 128, SPLITK), 256, 0, stream>>>(
      fbuf, D1, part, N_PP, N_PP, N_LP, N_PP, KCHUNK2, (size_t)(M_B * N_LP));

  reduce_out<<<(M_B * N_L + 255) / 256, 256, 0, stream>>>(part, out);
}

// Round 5
// 264.063 us; speedup vs baseline: 1.2848x; 1.0205x over previous
//
#include <hip/hip_runtime.h>
#include <hip/hip_bf16.h>
#include <stdint.h>

// Problem constants
#define M_B   1536      // 64*24 batch rows
#define N_L   500       // links
#define N_LP  512       // padded links (K of GEMM1, N of GEMM2)
#define N_P   20000     // paths
#define N_PP  20096     // padded paths (N of GEMM1 = 157*128, K of GEMM2)
#define N_G   4000      // OD groups
#define SPLITK 16
#define KCHUNK2 1280    // split-K chunk for GEMM2 (last chunk = 896, both %32==0)
#define NQ    8         // row split for softmax (eighths)
#define GQ    (N_G / NQ)   // 500 groups per block
#define NCH   4         // static chunks per thread: 4*1024 = 4096 path capacity
#define SM_CAP 4096     // LDS floats per softmax block (eighth ~2500, sigma~47 -> huge margin)

// Workspace layout (bytes). Total ~228 MB. partial aliases vp (vp dead after softmax).
#define OFF_A1   ((size_t)0)                    // bf16 [1536][512]      1,572,864
#define OFF_D1   ((size_t)1572864)              // bf16 [512][20096]    20,578,304
#define OFF_DT   ((size_t)22151168)             // bf16 [20096][512]    20,578,304
#define OFF_VP   ((size_t)42729472)             // f32  [1536][20096]  123,469,824
#define OFF_PART OFF_VP                         // f32  [16][1536][512] 50,331,648 (aliases vp)
#define OFF_F    ((size_t)166199296)            // bf16 [1536][20096]   61,734,912
#define OFF_BND  ((size_t)227934208)            // int  [4001]

typedef __bf16 bf16x8 __attribute__((ext_vector_type(8)));
typedef __bf16 bf16x4 __attribute__((ext_vector_type(4)));
typedef float  f32x4  __attribute__((ext_vector_type(4)));

__device__ __forceinline__ void gload16(const void* g, void* l) {
  __builtin_amdgcn_global_load_lds(
      (const __attribute__((address_space(1))) void*)g,
      (__attribute__((address_space(3))) void*)l, 16, 0, 0);
}

// monotonic float<->uint order-preserving mapping (for ds_max_u32-based float max)
__device__ __forceinline__ unsigned f2mono(float x) {
  unsigned u = __float_as_uint(x);
  return (u & 0x80000000u) ? ~u : (u | 0x80000000u);
}
__device__ __forceinline__ float mono2f(unsigned u) {
  u = (u & 0x80000000u) ? (u & 0x7fffffffu) : ~u;
  return __uint_as_float(u);
}

// ---- prep: v_links -> bf16 A1 [1536][512], zero-padded ----
__global__ __launch_bounds__(256) void prep_a1(const float* __restrict__ X,
                                               const float* __restrict__ theta,
                                               const float* __restrict__ theta_links,
                                               __bf16* __restrict__ A1) {
  int idx = blockIdx.x * 256 + threadIdx.x;           // over 1536*512
  if (idx >= M_B * N_LP) return;
  int b = idx >> 9, l = idx & (N_LP - 1);
  float v = 0.f;
  if (l < N_L) {
    const float* x = X + ((size_t)b * N_L + l) * 5;
#pragma unroll
    for (int f = 0; f < 5; ++f) v += x[f] * fminf(theta[f], 0.f);
    v += theta_links[l];
  }
  A1[idx] = (__bf16)v;
}

// ---- prep: D -> bf16 D1 [512][20096] (row copy) AND Dt [20096][512] (transpose),
//      both zero-padded; D read once. 32x32 tiles. ----
__global__ __launch_bounds__(256) void prep_d(const float* __restrict__ D,
                                              __bf16* __restrict__ D1,
                                              __bf16* __restrict__ Dt) {
  __shared__ float t[32][33];
  int pb = blockIdx.x * 32;   // path block
  int lb = blockIdx.y * 32;   // link block
  for (int i = threadIdx.y; i < 32; i += 8) {
    int l = lb + i, p = pb + threadIdx.x;
    float v = (l < N_L && p < N_P) ? D[(size_t)l * N_P + p] : 0.f;
    t[i][threadIdx.x] = v;
    D1[(size_t)l * N_PP + p] = (__bf16)v;
  }
  __syncthreads();
  for (int i = threadIdx.y; i < 32; i += 8) {
    int p = pb + i, l = lb + threadIdx.x;
    Dt[(size_t)p * N_LP + l] = (__bf16)t[threadIdx.x][i];
  }
}

// ---- segment bounds: bounds[g] = first path index with seg >= g, g in [0,4000] ----
__global__ __launch_bounds__(256) void seg_bounds(const int* __restrict__ seg,
                                                  int* __restrict__ bounds) {
  int g = blockIdx.x * 256 + threadIdx.x;
  if (g > N_G) return;
  int lo = 0, hi = N_P;
  while (lo < hi) { int mid = (lo + hi) >> 1; if (seg[mid] < g) lo = mid + 1; else hi = mid; }
  bounds[g] = lo;
}

// ---- GEMM (both A and Bt row-major over K): C[m][n] = sum_k A[m][k]*Bt[n][k] ----
__global__ __launch_bounds__(256) void gemm_bt(const __bf16* __restrict__ A,
                                               const __bf16* __restrict__ Bt,
                                               float* __restrict__ C,
                                               int lda, int ldb, int ldc,
                                               int K, int kchunk, size_t zstride) {
  __shared__ __bf16 lsA[128 * 32];
  __shared__ __bf16 lsB[128 * 32];
  const int tid = threadIdx.x;
  const int lane = tid & 63;
  const int wv = tid >> 6;
  const int wr = wv >> 1, wc = wv & 1;
  const int m0 = blockIdx.y * 128;
  const int n0 = blockIdx.x * 128;
  const int kb = blockIdx.z * kchunk;
  const int klen = min(kchunk, K - kb);

  const int srow = wv * 16 + (lane >> 2);
  const int scol = (lane & 3) * 8;
  const __bf16* gA = A + (size_t)(m0 + srow) * lda + kb + scol;
  const __bf16* gB = Bt + (size_t)(n0 + srow) * ldb + kb + scol;
  __bf16* lA0 = &lsA[(wv * 16) * 32];
  __bf16* lA1 = &lsA[(64 + wv * 16) * 32];
  __bf16* lB0 = &lsB[(wv * 16) * 32];
  __bf16* lB1 = &lsB[(64 + wv * 16) * 32];

  f32x4 acc[4][4] = {};
  const int fra = (wr * 64 + (lane & 15)) * 32 + 8 * (lane >> 4);
  const int frb = (wc * 64 + (lane & 15)) * 32 + 8 * (lane >> 4);

  for (int kk = 0; kk < klen; kk += 32) {
    gload16(gA + kk, lA0);
    gload16(gA + (size_t)64 * lda + kk, lA1);
    gload16(gB + kk, lB0);
    gload16(gB + (size_t)64 * ldb + kk, lB1);
    __syncthreads();
    bf16x8 av[4], bv[4];
#pragma unroll
    for (int r = 0; r < 4; ++r) av[r] = *(const bf16x8*)&lsA[fra + r * 16 * 32];
#pragma unroll
    for (int c = 0; c < 4; ++c) bv[c] = *(const bf16x8*)&lsB[frb + c * 16 * 32];
#pragma unroll
    for (int r = 0; r < 4; ++r)
#pragma unroll
      for (int c = 0; c < 4; ++c)
        acc[r][c] = __builtin_amdgcn_mfma_f32_16x16x32_bf16(av[r], bv[c], acc[r][c], 0, 0, 0);
    __syncthreads();
  }

  float* Cz = C + (size_t)blockIdx.z * zstride;
  const int erow = m0 + wr * 64 + (lane >> 4) * 4;
  const int ecol = n0 + wc * 64 + (lane & 15);
#pragma unroll
  for (int r = 0; r < 4; ++r)
#pragma unroll
    for (int c = 0; c < 4; ++c) {
      float* p = Cz + (size_t)(erow + r * 16) * ldc + (ecol + c * 16);
#pragma unroll
      for (int j = 0; j < 4; ++j) p[(size_t)j * ldc] = acc[r][c][j];
    }
}

// ---- grouped softmax: data-parallel over paths, values staged in LDS,
//      group reduce via LDS atomics (ds_max_u32 / ds_add_f32). ----
// blockIdx.x = row b, blockIdx.y = eighth (groups [q*GQ,(q+1)*GQ), paths [bounds[g0], e0)).
// Only seg indices (4 int4 = 16 VGPR, statically indexed) stay in registers.
__global__ __launch_bounds__(256) void seg_softmax(const float* __restrict__ vp,
                                                   const int* __restrict__ bounds,
                                                   const int* __restrict__ seg,
                                                   const float* __restrict__ q_sqrt,
                                                   __bf16* __restrict__ f) {
  __shared__ float    sr[SM_CAP];
  __shared__ unsigned gmaxu[GQ];
  __shared__ float    den[GQ];     // denom, then overwritten with scale q^2/denom
  const int tid = threadIdx.x;
  const int b = blockIdx.x;
  const int g0 = blockIdx.y * GQ;
  const int g1 = g0 + GQ;

  const unsigned NEGINF = f2mono(-3.4e38f);
  for (int i = tid; i < GQ; i += 256) { gmaxu[i] = NEGINF; den[i] = 0.f; }

  const int s0 = bounds[g0];
  const int e0 = (blockIdx.y == NQ - 1) ? N_P : bounds[g1];
  const int s0a = s0 & ~3;
  const int e0a = (e0 + 3) & ~3;
  const float* row = vp + (size_t)b * N_PP;

  int4 sgv[NCH];
  __syncthreads();   // init visible

  // pass 1: coalesced load -> LDS stage + run-combine atomic max
#define AMAX(g, m) { if ((g) >= g0 && (g) < g1) atomicMax(&gmaxu[(g) - g0], f2mono(m)); }
#pragma unroll
  for (int c = 0; c < NCH; ++c) {
    int p = s0a + (c * 256 + tid) * 4;
    if (p >= e0a) continue;
    f32x4 v = *(const f32x4*)&row[p];
    sgv[c] = *(const int4*)&seg[p];
    *(f32x4*)&sr[p - s0a] = v;
    int ga = sgv[c].x; float mv = v[0];
    if (sgv[c].y == ga) mv = fmaxf(mv, v[1]); else { AMAX(ga, mv); ga = sgv[c].y; mv = v[1]; }
    if (sgv[c].z == ga) mv = fmaxf(mv, v[2]); else { AMAX(ga, mv); ga = sgv[c].z; mv = v[2]; }
    if (sgv[c].w == ga) mv = fmaxf(mv, v[3]); else { AMAX(ga, mv); ga = sgv[c].w; mv = v[3]; }
    AMAX(ga, mv);
  }
#undef AMAX
  __syncthreads();

  // pass 2: exp (LDS read/write) + run-combine atomic add
#define AADD(g, s) { if ((g) >= g0 && (g) < g1) atomicAdd(&den[(g) - g0], s); }
#pragma unroll
  for (int c = 0; c < NCH; ++c) {
    int p = s0a + (c * 256 + tid) * 4;
    if (p >= e0a) continue;
    f32x4 v = *(const f32x4*)&sr[p - s0a];
    float t[4];
#pragma unroll
    for (int j = 0; j < 4; ++j) {
      int g = (&sgv[c].x)[j];
      bool valid = (g >= g0 && g < g1);
      float gm = valid ? mono2f(gmaxu[g - g0]) : 0.f;
      float e = valid ? __expf(v[j] - gm) : 0.f;
      t[j] = e;
      v[j] = e;
    }
    *(f32x4*)&sr[p - s0a] = v;
    int ga = sgv[c].x; float s = t[0];
    if (sgv[c].y == ga) s += t[1]; else { AADD(ga, s); ga = sgv[c].y; s = t[1]; }
    if (sgv[c].z == ga) s += t[2]; else { AADD(ga, s); ga = sgv[c].z; s = t[2]; }
    if (sgv[c].w == ga) s += t[3]; else { AADD(ga, s); ga = sgv[c].w; s = t[3]; }
    AADD(ga, s);
  }
#undef AADD
  __syncthreads();

  // den -> scale = q^2 / den
  for (int g = tid; g < GQ; g += 256) {
    float d = den[g];
    if (d > 0.f) {
      float qs = q_sqrt[g0 + g];
      den[g] = qs * qs / d;
    }
  }
  __syncthreads();

  // pass 3: scale + store (vector where the whole chunk is in-range)
  __bf16* frow = f + (size_t)b * N_PP;
#pragma unroll
  for (int c = 0; c < NCH; ++c) {
    int p = s0a + (c * 256 + tid) * 4;
    if (p >= e0a) continue;
    f32x4 v = *(const f32x4*)&sr[p - s0a];
    bool allv = (sgv[c].x >= g0) && (sgv[c].w < g1);
    if (allv) {
      bf16x4 o;
      o[0] = (__bf16)(v[0] * den[sgv[c].x - g0]);
      o[1] = (__bf16)(v[1] * den[sgv[c].y - g0]);
      o[2] = (__bf16)(v[2] * den[sgv[c].z - g0]);
      o[3] = (__bf16)(v[3] * den[sgv[c].w - g0]);
      *(bf16x4*)&frow[p] = o;
    } else {
#pragma unroll
      for (int j = 0; j < 4; ++j) {
        int g = (&sgv[c].x)[j];
        if (g >= g0 && g < g1) frow[p + j] = (__bf16)(v[j] * den[g - g0]);
      }
    }
  }
  // zero padded tail so GEMM2's K-padding contributes nothing
  if (blockIdx.y == NQ - 1)
    for (int p = N_P + tid; p < N_PP; p += 256) frow[p] = (__bf16)0.f;
}

// ---- reduce split-K partials -> out (only l < 500) ----
__global__ __launch_bounds__(256) void reduce_out(const float* __restrict__ part,
                                                  float* __restrict__ out) {
  int idx = blockIdx.x * 256 + threadIdx.x;   // over 1536*500
  if (idx >= M_B * N_L) return;
  int b = idx / N_L, l = idx - b * N_L;
  float s = 0.f;
#pragma unroll
  for (int z = 0; z < SPLITK; ++z)
    s += part[(size_t)z * M_B * N_LP + (size_t)b * N_LP + l];
  out[idx] = s;
}

extern "C" void kernel_launch(void* const* d_in, const int* in_sizes, int n_in,
                              void* d_out, int out_size, void* d_ws, size_t ws_size,
                              hipStream_t stream) {
  const float* X           = (const float*)d_in[0];
  const float* theta       = (const float*)d_in[1];
  const float* theta_links = (const float*)d_in[2];
  const float* q_sqrt      = (const float*)d_in[3];
  const float* D           = (const float*)d_in[4];
  const int*   seg         = (const int*)d_in[5];
  float* out = (float*)d_out;

  char* ws = (char*)d_ws;
  __bf16* A1   = (__bf16*)(ws + OFF_A1);
  __bf16* D1   = (__bf16*)(ws + OFF_D1);
  __bf16* Dt   = (__bf16*)(ws + OFF_DT);
  float*  vp   = (float*)(ws + OFF_VP);
  float*  part = (float*)(ws + OFF_PART);
  __bf16* fbuf = (__bf16*)(ws + OFF_F);
  int*    bnd  = (int*)(ws + OFF_BND);

  prep_a1<<<(M_B * N_LP) / 256, 256, 0, stream>>>(X, theta, theta_links, A1);
  prep_d<<<dim3(N_PP / 32, N_LP / 32), dim3(32, 8), 0, stream>>>(D, D1, Dt);
  seg_bounds<<<16, 256, 0, stream>>>(seg, bnd);

  // GEMM1: vp[b][p] = sum_l A1[b][l] * Dt[p][l]
  gemm_bt<<<dim3(N_PP / 128, M_B / 128, 1), 256, 0, stream>>>(
      A1, Dt, vp, N_LP, N_LP, N_PP, N_LP, N_LP, (size_t)0);

  seg_softmax<<<dim3(M_B, NQ), 256, 0, stream>>>(vp, bnd, seg, q_sqrt, fbuf);

  // GEMM2 (split-K): part[z][b][l] = sum_{k in chunk z} f[b][k] * D1[l][k]
  gemm_bt<<<dim3(N_LP / 128, M_B / 128, SPLITK), 256, 0, stream>>>(
      fbuf, D1, part, N_PP, N_PP, N_LP, N_PP, KCHUNK2, (size_t)(M_B * N_LP));

  reduce_out<<<(M_B * N_L + 255) / 256, 256, 0, stream>>>(part, out);
}

// Round 6
// 258.159 us; speedup vs baseline: 1.3141x; 1.0229x over previous
//
#include <hip/hip_runtime.h>
#include <hip/hip_bf16.h>
#include <stdint.h>

// Problem constants
#define M_B   1536      // 64*24 batch rows
#define N_L   500       // links
#define N_LP  512       // padded links (K of GEMM1, N of GEMM2)
#define N_P   20000     // paths
#define N_PP  20096     // padded paths (N of GEMM1 = 157*128, K of GEMM2)
#define N_G   4000      // OD groups
#define SPLITK 16
#define KCHUNK2 1280    // split-K chunk for GEMM2 (last chunk = 896, both %32==0)
#define NQ    8         // row split for softmax (eighths)
#define GQ    (N_G / NQ)   // 500 groups per block
#define NCH   4         // static chunks per thread: 4*1024 = 4096 path capacity (~2500 used, 24 sigma margin)

// Workspace layout (bytes). Total ~228 MB. partial aliases vp (vp dead after softmax).
#define OFF_A1   ((size_t)0)                    // bf16 [1536][512]      1,572,864
#define OFF_D1   ((size_t)1572864)              // bf16 [512][20096]    20,578,304
#define OFF_DT   ((size_t)22151168)             // bf16 [20096][512]    20,578,304
#define OFF_VP   ((size_t)42729472)             // f32  [1536][20096]  123,469,824
#define OFF_PART OFF_VP                         // f32  [16][1536][512] 50,331,648 (aliases vp)
#define OFF_F    ((size_t)166199296)            // bf16 [1536][20096]   61,734,912
#define OFF_BND  ((size_t)227934208)            // int  [4001]

typedef __bf16 bf16x8 __attribute__((ext_vector_type(8)));
typedef __bf16 bf16x4 __attribute__((ext_vector_type(4)));
typedef float  f32x4  __attribute__((ext_vector_type(4)));

__device__ __forceinline__ void gload16(const void* g, void* l) {
  __builtin_amdgcn_global_load_lds(
      (const __attribute__((address_space(1))) void*)g,
      (__attribute__((address_space(3))) void*)l, 16, 0, 0);
}

// monotonic float<->uint order-preserving mapping (for ds_max_u32-based float max)
__device__ __forceinline__ unsigned f2mono(float x) {
  unsigned u = __float_as_uint(x);
  return (u & 0x80000000u) ? ~u : (u | 0x80000000u);
}
__device__ __forceinline__ float mono2f(unsigned u) {
  u = (u & 0x80000000u) ? (u & 0x7fffffffu) : ~u;
  return __uint_as_float(u);
}

// ---- prep: v_links -> bf16 A1 [1536][512], zero-padded ----
__global__ __launch_bounds__(256) void prep_a1(const float* __restrict__ X,
                                               const float* __restrict__ theta,
                                               const float* __restrict__ theta_links,
                                               __bf16* __restrict__ A1) {
  int idx = blockIdx.x * 256 + threadIdx.x;           // over 1536*512
  if (idx >= M_B * N_LP) return;
  int b = idx >> 9, l = idx & (N_LP - 1);
  float v = 0.f;
  if (l < N_L) {
    const float* x = X + ((size_t)b * N_L + l) * 5;
#pragma unroll
    for (int f = 0; f < 5; ++f) v += x[f] * fminf(theta[f], 0.f);
    v += theta_links[l];
  }
  A1[idx] = (__bf16)v;
}

// ---- prep: D -> bf16 D1 [512][20096] (row copy) AND Dt [20096][512] (transpose),
//      both zero-padded; D read once. 32x32 tiles. ----
__global__ __launch_bounds__(256) void prep_d(const float* __restrict__ D,
                                              __bf16* __restrict__ D1,
                                              __bf16* __restrict__ Dt) {
  __shared__ float t[32][33];
  int pb = blockIdx.x * 32;   // path block
  int lb = blockIdx.y * 32;   // link block
  for (int i = threadIdx.y; i < 32; i += 8) {
    int l = lb + i, p = pb + threadIdx.x;
    float v = (l < N_L && p < N_P) ? D[(size_t)l * N_P + p] : 0.f;
    t[i][threadIdx.x] = v;
    D1[(size_t)l * N_PP + p] = (__bf16)v;
  }
  __syncthreads();
  for (int i = threadIdx.y; i < 32; i += 8) {
    int p = pb + i, l = lb + threadIdx.x;
    Dt[(size_t)p * N_LP + l] = (__bf16)t[threadIdx.x][i];
  }
}

// ---- segment bounds: bounds[g] = first path index with seg >= g, g in [0,4000] ----
__global__ __launch_bounds__(256) void seg_bounds(const int* __restrict__ seg,
                                                  int* __restrict__ bounds) {
  int g = blockIdx.x * 256 + threadIdx.x;
  if (g > N_G) return;
  int lo = 0, hi = N_P;
  while (lo < hi) { int mid = (lo + hi) >> 1; if (seg[mid] < g) lo = mid + 1; else hi = mid; }
  bounds[g] = lo;
}

// ---- GEMM (both A and Bt row-major over K): C[m][n] = sum_k A[m][k]*Bt[n][k] ----
__global__ __launch_bounds__(256) void gemm_bt(const __bf16* __restrict__ A,
                                               const __bf16* __restrict__ Bt,
                                               float* __restrict__ C,
                                               int lda, int ldb, int ldc,
                                               int K, int kchunk, size_t zstride) {
  __shared__ __bf16 lsA[128 * 32];
  __shared__ __bf16 lsB[128 * 32];
  const int tid = threadIdx.x;
  const int lane = tid & 63;
  const int wv = tid >> 6;
  const int wr = wv >> 1, wc = wv & 1;
  const int m0 = blockIdx.y * 128;
  const int n0 = blockIdx.x * 128;
  const int kb = blockIdx.z * kchunk;
  const int klen = min(kchunk, K - kb);

  const int srow = wv * 16 + (lane >> 2);
  const int scol = (lane & 3) * 8;
  const __bf16* gA = A + (size_t)(m0 + srow) * lda + kb + scol;
  const __bf16* gB = Bt + (size_t)(n0 + srow) * ldb + kb + scol;
  __bf16* lA0 = &lsA[(wv * 16) * 32];
  __bf16* lA1 = &lsA[(64 + wv * 16) * 32];
  __bf16* lB0 = &lsB[(wv * 16) * 32];
  __bf16* lB1 = &lsB[(64 + wv * 16) * 32];

  f32x4 acc[4][4] = {};
  const int fra = (wr * 64 + (lane & 15)) * 32 + 8 * (lane >> 4);
  const int frb = (wc * 64 + (lane & 15)) * 32 + 8 * (lane >> 4);

  for (int kk = 0; kk < klen; kk += 32) {
    gload16(gA + kk, lA0);
    gload16(gA + (size_t)64 * lda + kk, lA1);
    gload16(gB + kk, lB0);
    gload16(gB + (size_t)64 * ldb + kk, lB1);
    __syncthreads();
    bf16x8 av[4], bv[4];
#pragma unroll
    for (int r = 0; r < 4; ++r) av[r] = *(const bf16x8*)&lsA[fra + r * 16 * 32];
#pragma unroll
    for (int c = 0; c < 4; ++c) bv[c] = *(const bf16x8*)&lsB[frb + c * 16 * 32];
#pragma unroll
    for (int r = 0; r < 4; ++r)
#pragma unroll
      for (int c = 0; c < 4; ++c)
        acc[r][c] = __builtin_amdgcn_mfma_f32_16x16x32_bf16(av[r], bv[c], acc[r][c], 0, 0, 0);
    __syncthreads();
  }

  float* Cz = C + (size_t)blockIdx.z * zstride;
  const int erow = m0 + wr * 64 + (lane >> 4) * 4;
  const int ecol = n0 + wc * 64 + (lane & 15);
#pragma unroll
  for (int r = 0; r < 4; ++r)
#pragma unroll
    for (int c = 0; c < 4; ++c) {
      float* p = Cz + (size_t)(erow + r * 16) * ldc + (ecol + c * 16);
#pragma unroll
      for (int j = 0; j < 4; ++j) p[(size_t)j * ldc] = acc[r][c][j];
    }
}

// ---- grouped softmax: data-parallel over paths, values fully in REGISTERS,
//      group reduce via LDS atomics (ds_max_u32 / ds_add_f32). ----
// blockIdx.x = row b, blockIdx.y = eighth (groups [q*GQ,(q+1)*GQ), paths [bounds[g0], e0)).
// vv[NCH] f32x4 (16 VGPR) + sgv[NCH] int4 (16 VGPR), all statically indexed -> no scratch.
__global__ __launch_bounds__(256) void seg_softmax(const float* __restrict__ vp,
                                                   const int* __restrict__ bounds,
                                                   const int* __restrict__ seg,
                                                   const float* __restrict__ q_sqrt,
                                                   __bf16* __restrict__ f) {
  __shared__ unsigned gmaxu[GQ];
  __shared__ float    den[GQ];     // denom, then overwritten with scale q^2/denom
  const int tid = threadIdx.x;
  const int b = blockIdx.x;
  const int g0 = blockIdx.y * GQ;
  const int g1 = g0 + GQ;

  const unsigned NEGINF = f2mono(-3.4e38f);
  for (int i = tid; i < GQ; i += 256) { gmaxu[i] = NEGINF; den[i] = 0.f; }

  const int s0 = bounds[g0];
  const int e0 = (blockIdx.y == NQ - 1) ? N_P : bounds[g1];
  const int s0a = s0 & ~3;
  const int e0a = (e0 + 3) & ~3;
  const float* row = vp + (size_t)b * N_PP;

  f32x4 vv[NCH];
  int4  sgv[NCH];
  __syncthreads();   // init visible

  // pass 1: coalesced load into registers + run-combine atomic max
#define AMAX(g, m) { if ((g) >= g0 && (g) < g1) atomicMax(&gmaxu[(g) - g0], f2mono(m)); }
#pragma unroll
  for (int c = 0; c < NCH; ++c) {
    int p = s0a + (c * 256 + tid) * 4;
    if (p >= e0a) continue;
    f32x4 v = *(const f32x4*)&row[p];
    vv[c] = v;
    sgv[c] = *(const int4*)&seg[p];
    int ga = sgv[c].x; float mv = v[0];
    if (sgv[c].y == ga) mv = fmaxf(mv, v[1]); else { AMAX(ga, mv); ga = sgv[c].y; mv = v[1]; }
    if (sgv[c].z == ga) mv = fmaxf(mv, v[2]); else { AMAX(ga, mv); ga = sgv[c].z; mv = v[2]; }
    if (sgv[c].w == ga) mv = fmaxf(mv, v[3]); else { AMAX(ga, mv); ga = sgv[c].w; mv = v[3]; }
    AMAX(ga, mv);
  }
#undef AMAX
  __syncthreads();

  // pass 2: exp in registers + run-combine atomic add
#define AADD(g, s) { if ((g) >= g0 && (g) < g1) atomicAdd(&den[(g) - g0], s); }
#pragma unroll
  for (int c = 0; c < NCH; ++c) {
    int p = s0a + (c * 256 + tid) * 4;
    if (p >= e0a) continue;
    float t[4];
#pragma unroll
    for (int j = 0; j < 4; ++j) {
      int g = (&sgv[c].x)[j];
      bool valid = (g >= g0 && g < g1);
      float gm = valid ? mono2f(gmaxu[g - g0]) : 0.f;
      float e = valid ? __expf(vv[c][j] - gm) : 0.f;
      t[j] = e;
      vv[c][j] = e;
    }
    int ga = sgv[c].x; float s = t[0];
    if (sgv[c].y == ga) s += t[1]; else { AADD(ga, s); ga = sgv[c].y; s = t[1]; }
    if (sgv[c].z == ga) s += t[2]; else { AADD(ga, s); ga = sgv[c].z; s = t[2]; }
    if (sgv[c].w == ga) s += t[3]; else { AADD(ga, s); ga = sgv[c].w; s = t[3]; }
    AADD(ga, s);
  }
#undef AADD
  __syncthreads();

  // den -> scale = q^2 / den
  for (int g = tid; g < GQ; g += 256) {
    float d = den[g];
    if (d > 0.f) {
      float qs = q_sqrt[g0 + g];
      den[g] = qs * qs / d;
    }
  }
  __syncthreads();

  // pass 3: scale + store (vector where the whole chunk is in-range)
  __bf16* frow = f + (size_t)b * N_PP;
#pragma unroll
  for (int c = 0; c < NCH; ++c) {
    int p = s0a + (c * 256 + tid) * 4;
    if (p >= e0a) continue;
    bool allv = (sgv[c].x >= g0) && (sgv[c].w < g1);
    if (allv) {
      bf16x4 o;
      o[0] = (__bf16)(vv[c][0] * den[sgv[c].x - g0]);
      o[1] = (__bf16)(vv[c][1] * den[sgv[c].y - g0]);
      o[2] = (__bf16)(vv[c][2] * den[sgv[c].z - g0]);
      o[3] = (__bf16)(vv[c][3] * den[sgv[c].w - g0]);
      *(bf16x4*)&frow[p] = o;
    } else {
#pragma unroll
      for (int j = 0; j < 4; ++j) {
        int g = (&sgv[c].x)[j];
        if (g >= g0 && g < g1) frow[p + j] = (__bf16)(vv[c][j] * den[g - g0]);
      }
    }
  }
  // zero padded tail so GEMM2's K-padding contributes nothing
  if (blockIdx.y == NQ - 1)
    for (int p = N_P + tid; p < N_PP; p += 256) frow[p] = (__bf16)0.f;
}

// ---- reduce split-K partials -> out (only l < 500) ----
__global__ __launch_bounds__(256) void reduce_out(const float* __restrict__ part,
                                                  float* __restrict__ out) {
  int idx = blockIdx.x * 256 + threadIdx.x;   // over 1536*500
  if (idx >= M_B * N_L) return;
  int b = idx / N_L, l = idx - b * N_L;
  float s = 0.f;
#pragma unroll
  for (int z = 0; z < SPLITK; ++z)
    s += part[(size_t)z * M_B * N_LP + (size_t)b * N_LP + l];
  out[idx] = s;
}

extern "C" void kernel_launch(void* const* d_in, const int* in_sizes, int n_in,
                              void* d_out, int out_size, void* d_ws, size_t ws_size,
                              hipStream_t stream) {
  const float* X           = (const float*)d_in[0];
  const float* theta       = (const float*)d_in[1];
  const float* theta_links = (const float*)d_in[2];
  const float* q_sqrt      = (const float*)d_in[3];
  const float* D           = (const float*)d_in[4];
  const int*   seg         = (const int*)d_in[5];
  float* out = (float*)d_out;

  char* ws = (char*)d_ws;
  __bf16* A1   = (__bf16*)(ws + OFF_A1);
  __bf16* D1   = (__bf16*)(ws + OFF_D1);
  __bf16* Dt   = (__bf16*)(ws + OFF_DT);
  float*  vp   = (float*)(ws + OFF_VP);
  float*  part = (float*)(ws + OFF_PART);
  __bf16* fbuf = (__bf16*)(ws + OFF_F);
  int*    bnd  = (int*)(ws + OFF_BND);

  prep_a1<<<(M_B * N_LP) / 256, 256, 0, stream>>>(X, theta, theta_links, A1);
  prep_d<<<dim3(N_PP / 32, N_LP / 32), dim3(32, 8), 0, stream>>>(D, D1, Dt);
  seg_bounds<<<16, 256, 0, stream>>>(seg, bnd);

  // GEMM1: vp[b][p] = sum_l A1[b][l] * Dt[p][l]
  gemm_bt<<<dim3(N_PP / 128, M_B / 128, 1), 256, 0, stream>>>(
      A1, Dt, vp, N_LP, N_LP, N_PP, N_LP, N_LP, (size_t)0);

  seg_softmax<<<dim3(M_B, NQ), 256, 0, stream>>>(vp, bnd, seg, q_sqrt, fbuf);

  // GEMM2 (split-K): part[z][b][l] = sum_{k in chunk z} f[b][k] * D1[l][k]
  gemm_bt<<<dim3(N_LP / 128, M_B / 128, SPLITK), 256, 0, stream>>>(
      fbuf, D1, part, N_PP, N_PP, N_LP, N_PP, KCHUNK2, (size_t)(M_B * N_LP));

  reduce_out<<<(M_B * N_L + 255) / 256, 256, 0, stream>>>(part, out);
}